// Round 13
// baseline (149.328 us; speedup 1.0000x reference)
//
#include <hip/hip_runtime.h>
#include <hip/hip_bf16.h>
#include <math.h>

#define NEXP  16
#define SEQ   512
#define PRED  720
#define NROWS 8192
#define NFREQ 256

typedef __bf16 bf16x8 __attribute__((ext_vector_type(8)));
typedef float  f32x16 __attribute__((ext_vector_type(16)));

__device__ __forceinline__ void gload_lds16(const void* g, void* l) {
    __builtin_amdgcn_global_load_lds(
        (const __attribute__((address_space(1))) unsigned int*)g,
        (__attribute__((address_space(3))) unsigned int*)l, 16, 0, 0);
}

// bijective XCD swizzle (m204)
__device__ __forceinline__ int xcd_swizzle(int bid, int nwg) {
    const int q = nwg >> 3, r = nwg & 7;
    const int xcd = bid & 7, off = bid >> 3;
    return (xcd < r ? xcd * (q + 1) : r * (q + 1) + (xcd - r) * q) + off;
}

// ---------------- K0: fused preprocessing (build_dft | transpose_ew | stats) ---------
__global__ __launch_bounds__(256) void k_preproc(const float* __restrict__ ew,
                                                 const float* __restrict__ x,
                                                 __hip_bfloat16* __restrict__ ewt,
                                                 __hip_bfloat16* __restrict__ bthi,
                                                 __hip_bfloat16* __restrict__ btlo,
                                                 __hip_bfloat16* __restrict__ xn,
                                                 __hip_bfloat16* __restrict__ xnlo,
                                                 float* __restrict__ meta,
                                                 int* __restrict__ nredo)
{
    const int bid = blockIdx.x;
    const int t   = threadIdx.x;

    if (bid < 512) {
        if (bid == 0 && t == 0) *nredo = 0;
        const int tid  = bid * 256 + t;
        const int f    = tid >> 9;
        const int lidx = tid & 511;
        const int m    = (f * lidx) & 511;

        constexpr double Cj[9] = {0.9999247018391445033, 0.9996988186962042201,
                                  0.9987954562051723927, 0.9951847266721968862,
                                  0.9807852804032304491, 0.9238795325112867561,
                                  0.7071067811865475244, 0.0, -1.0};
        constexpr double Sj[9] = {0.0122715382857199261, 0.0245412285229122880,
                                  0.0490676743274180143, 0.0980171403295606020,
                                  0.1950903220161282678, 0.3826834323650897717,
                                  0.7071067811865475244, 1.0, 0.0};
        double cr = 1.0, ci = 0.0;
#pragma unroll
        for (int j = 0; j < 9; ++j) {
            const bool on = (m >> j) & 1;
            const double mr = on ? Cj[j] : 1.0;
            const double mi = on ? Sj[j] : 0.0;
            const double nr = cr * mr - ci * mi;
            ci = cr * mi + ci * mr;
            cr = nr;
        }
        const size_t c0 = (size_t)(2 * f) * 512 + lidx;
        const size_t c1 = (size_t)(2 * f + 1) * 512 + lidx;
        {
            __hip_bfloat16 h = __float2bfloat16((float)cr);
            float hif = __bfloat162float(h);
            bthi[c0] = h;
            btlo[c0] = __float2bfloat16((float)(cr - (double)hif));
        }
        {
            __hip_bfloat16 h = __float2bfloat16((float)ci);
            float hif = __bfloat162float(h);
            bthi[c1] = h;
            btlo[c1] = __float2bfloat16((float)(ci - (double)hif));
        }
        return;
    }

    if (bid < 6400) {
        __shared__ float tile[32][33];
        const int rel = bid - 512;
        const int e   = rel / 368;
        const int rem = rel % 368;
        const int p0  = (rem % 23) * 32;
        const int l0  = (rem / 23) * 32;
        const int tx  = t & 31;
        const int ty  = t >> 5;
        const float* src = ew + (size_t)e * SEQ * PRED;
#pragma unroll
        for (int i = 0; i < 4; ++i) {
            int l = l0 + ty + i * 8;
            int p = p0 + tx;
            tile[ty + i * 8][tx] = (p < PRED) ? src[(size_t)l * PRED + p] : 0.f;
        }
        __syncthreads();
        __hip_bfloat16* dst = ewt + (size_t)e * PRED * SEQ;
#pragma unroll
        for (int i = 0; i < 4; ++i) {
            int p = p0 + ty + i * 8;
            int l = l0 + tx;
            if (p < PRED) dst[(size_t)p * SEQ + l] = __float2bfloat16(tile[tx][ty + i * 8]);
        }
        return;
    }

    {
        const int wv = t >> 6, l = t & 63;
        const int b  = (bid - 6400) * 4 + wv;
        const float* xr = x + (size_t)b * SEQ;

        const float4 v0 = *(const float4*)(xr + l * 8);
        const float4 v1 = *(const float4*)(xr + l * 8 + 4);
        const double d0 = v0.x, d1 = v0.y, d2 = v0.z, d3 = v0.w;
        const double d4 = v1.x, d5 = v1.y, d6 = v1.z, d7 = v1.w;

        double s1 = ((d0 + d1) + (d2 + d3)) + ((d4 + d5) + (d6 + d7));
        double s2 = ((d0 * d0 + d1 * d1) + (d2 * d2 + d3 * d3)) +
                    ((d4 * d4 + d5 * d5) + (d6 * d6 + d7 * d7));
#pragma unroll
        for (int off = 1; off < 64; off <<= 1) {
            s1 += __shfl_xor(s1, off);
            s2 += __shfl_xor(s2, off);
        }
        const double mu = s1 * (1.0 / 512.0);
        double var = s2 * (1.0 / 512.0) - mu * mu;
        if (var < 0.0) var = 0.0;
        const double sd = sqrt(var) + 1e-5, inv = 1.0 / sd;

        unsigned int hw[4], lw[4];
#define CONV(j, dj)                                                         \
        {                                                                   \
            double xnd = (dj - mu) * inv;                                   \
            __hip_bfloat16 h = __float2bfloat16((float)xnd);                \
            float hif = __bfloat162float(h);                                \
            __hip_bfloat16 lo = __float2bfloat16((float)(xnd - (double)hif)); \
            unsigned int hb = *(unsigned short*)&h;                         \
            unsigned int lb = *(unsigned short*)&lo;                        \
            if ((j & 1) == 0) { hw[j >> 1] = hb; lw[j >> 1] = lb; }         \
            else { hw[j >> 1] |= hb << 16; lw[j >> 1] |= lb << 16; }        \
        }
        CONV(0, d0) CONV(1, d1) CONV(2, d2) CONV(3, d3)
        CONV(4, d4) CONV(5, d5) CONV(6, d6) CONV(7, d7)
#undef CONV
        *(uint4*)(xn   + (size_t)b * SEQ + l * 8) = uint4{hw[0], hw[1], hw[2], hw[3]};
        *(uint4*)(xnlo + (size_t)b * SEQ + l * 8) = uint4{lw[0], lw[1], lw[2], lw[3]};

        if (l == 0) {
            meta[b * 4 + 0] = (float)mu;
            meta[b * 4 + 3] = (float)sd;
        }
    }
}

// ---------------- K1: DFT as GEMM, 64x64 tile, BK=32, 3-buffer ring (25 KB LDS) ------
__global__ __launch_bounds__(256, 6) void k_dft_gemm(
    const __hip_bfloat16* __restrict__ xn, const __hip_bfloat16* __restrict__ xnlo,
    const __hip_bfloat16* __restrict__ bthi, const __hip_bfloat16* __restrict__ btlo,
    float* __restrict__ Iout)
{
    const int wgid = xcd_swizzle(blockIdx.x, 1024);
    const int rt = wgid >> 3;
    const int ct = wgid & 7;

    __shared__ __align__(16) __hip_bfloat16 As[3][64][32];
    __shared__ __align__(16) __hip_bfloat16 Bs[3][64][32];

    const int t  = threadIdx.x;
    const int wv = t >> 6, l = t & 63;

    // stage mapping: row = t>>2 (0..63), chunk = t&3 (16B); source chunk pre-swizzled
    const int srow = t >> 2, schk = t & 3;
    const int sswz = (srow >> 1) & 3;
    const size_t aoff = (size_t)(rt * 64 + srow) * SEQ + (size_t)(schk ^ sswz) * 8;
    const size_t boff = (size_t)(ct * 64 + srow) * SEQ + (size_t)(schk ^ sswz) * 8;

#define DSTAGE(buf, kk) do {                                                   \
    const int pass_ = (kk) >> 4;                                               \
    const int koff_ = ((kk) & 15) * 32;                                        \
    const __hip_bfloat16* ap_ = (pass_ == 1) ? xnlo : xn;                      \
    const __hip_bfloat16* bp_ = (pass_ == 2) ? btlo : bthi;                    \
    gload_lds16(ap_ + aoff + koff_, &As[buf][srow][schk * 8]);                 \
    gload_lds16(bp_ + boff + koff_, &Bs[buf][srow][schk * 8]);                 \
} while (0)

    f32x16 acc;
#pragma unroll
    for (int q = 0; q < 16; ++q) acc[q] = 0.f;

    const int wr = wv >> 1, wc = wv & 1;
    const int fl = l & 31, fh = l >> 5;
    const int rswz = (fl >> 1) & 3;

    DSTAGE(0, 0);
    DSTAGE(1, 1);
#pragma unroll
    for (int kt = 0; kt < 48; ++kt) {
        const int cur = kt % 3;
        if (kt < 47) asm volatile("s_waitcnt vmcnt(2)" ::: "memory");
        else         asm volatile("s_waitcnt vmcnt(0)" ::: "memory");
        __builtin_amdgcn_sched_barrier(0);
        __builtin_amdgcn_s_barrier();
        __builtin_amdgcn_sched_barrier(0);
#pragma unroll
        for (int ks = 0; ks < 2; ++ks) {
            const int cc = ((ks * 2 + fh) ^ rswz) * 8;
            const bf16x8 a = *(const bf16x8*)&As[cur][wr * 32 + fl][cc];
            const bf16x8 b = *(const bf16x8*)&Bs[cur][wc * 32 + fl][cc];
            acc = __builtin_amdgcn_mfma_f32_32x32x16_bf16(a, b, acc, 0, 0, 0);
        }
        if (kt + 2 < 48) DSTAGE((kt + 2) % 3, kt + 2);
    }
#undef DSTAGE

    const int crow_base = 4 * fh;
    const int col = ct * 64 + wc * 32 + fl;
#pragma unroll
    for (int q = 0; q < 16; ++q) {
        const float v = acc[q];
        const float w = __shfl_xor(v, 1);
        if ((fl & 1) == 0) {
            const int rl = wr * 32 + (q & 3) + 8 * (q >> 2) + crow_base;
            Iout[(size_t)(rt * 64 + rl) * NFREQ + (col >> 1)] = v * v + w * w;
        }
    }
}

// ---------------- K2: gate finalize (no contended atomics) ---------------------------
__global__ __launch_bounds__(256) void k_gatefin(const float* __restrict__ Iout,
                                                 const float* __restrict__ gw,
                                                 const float* __restrict__ gb,
                                                 float* __restrict__ meta,
                                                 int* __restrict__ eidx,
                                                 int* __restrict__ redo,
                                                 int* __restrict__ nredo)
{
    __shared__ float gws[NEXP * 257];
    __shared__ float Pw[4][256];
    __shared__ float Gs[4][16];

    const int t  = threadIdx.x;
    const int wv = t >> 6, l = t & 63;
    const int b  = blockIdx.x * 4 + wv;

    for (int i = t; i < NEXP * NFREQ; i += 256)
        gws[(i >> 8) * 257 + (i & 255)] = gw[i];
    __syncthreads();

    const float* Ir = Iout + (size_t)b * NFREQ;
    const float i0 = Ir[l], i1 = Ir[64 + l], i2 = Ir[128 + l], i3 = Ir[192 + l];
    Pw[wv][l] = i0; Pw[wv][64 + l] = i1; Pw[wv][128 + l] = i2; Pw[wv][192 + l] = i3;
    float ps = (i0 + i1) + (i2 + i3);
#pragma unroll
    for (int off = 1; off < 64; off <<= 1) ps += __shfl_xor(ps, off);

    const int e = l >> 2, kb = l & 3;
    float acc = 0.f;
#pragma unroll 8
    for (int j = 0; j < 64; ++j) {
        const int k = kb + 4 * j;
        acc += Pw[wv][k] * gws[e * 257 + k];
    }
    acc += __shfl_xor(acc, 1);
    acc += __shfl_xor(acc, 2);
    if (kb == 0) Gs[wv][e] = acc;

    if (l == 0) {
        const float sdiv  = (ps == 0.f) ? 1.f : ps;
        const float inv_s = 1.f / sdiv;
        float b1 = -1e30f, b2 = -1e30f, b3 = -1e30f;
        int i1b = 0, i2b = 0;
#pragma unroll
        for (int i = 0; i < NEXP; ++i) {
            float v = Gs[wv][i] * inv_s + gb[i];
            if (v > b1)      { b3 = b2; b2 = b1; i2b = i1b; b1 = v; i1b = i; }
            else if (v > b2) { b3 = b2; b2 = v; i2b = i; }
            else if (v > b3) { b3 = v; }
        }
        if (b2 - b3 < 1e-4f * fmaxf(1.f, fabsf(b1))) {
            const int r = atomicAdd(nredo, 1);
            redo[r] = b;
        } else {
            const float sd = meta[b * 4 + 3];
            const float ee = __expf(b2 - b1);
            const float w0 = 1.f / (1.f + ee);
            const float w1 = ee / (1.f + ee);
            meta[b * 4 + 1] = w0 * sd;
            meta[b * 4 + 2] = w1 * sd;
            eidx[b * 2 + 0] = i1b;
            eidx[b * 2 + 1] = i2b;
        }
    }
}

// ---------------- K3: fp64 recheck of ambiguous rows ---------------------------------
__global__ __launch_bounds__(256, 4) void k_gate64(const float* __restrict__ x,
                                                   const float* __restrict__ gw,
                                                   const float* __restrict__ gb,
                                                   float* __restrict__ meta,
                                                   int* __restrict__ eidx,
                                                   const int* __restrict__ redo,
                                                   const int* __restrict__ nredo)
{
    __shared__ double Pw[4][256];
    __shared__ double Gs[4][16];

    const int t  = threadIdx.x;
    const int wv = t >> 6, l = t & 63;
    const int n  = *nredo;

    for (int it = blockIdx.x * 4 + wv; it < n; it += gridDim.x * 4) {
        const int b = redo[it];
        const float* xr = x + (size_t)b * SEQ;

        double s1 = 0.0, s2 = 0.0;
#define DLOADV(n_) double vr##n_ = (double)xr[64 * n_ + l]; s1 += vr##n_; s2 += vr##n_ * vr##n_;
        DLOADV(0) DLOADV(1) DLOADV(2) DLOADV(3) DLOADV(4) DLOADV(5) DLOADV(6) DLOADV(7)
#undef DLOADV
        double vi0, vi1, vi2, vi3, vi4, vi5, vi6, vi7;

#pragma unroll
        for (int off = 1; off < 64; off <<= 1) {
            s1 += __shfl_xor(s1, off);
            s2 += __shfl_xor(s2, off);
        }
        const double mu = s1 * (1.0 / 512.0);
        double var = s2 * (1.0 / 512.0) - mu * mu;
        if (var < 0.0) var = 0.0;
        const double sd = sqrt(var) + 1e-5;

#define DSUB(n_) vr##n_ -= mu;
        DSUB(0) DSUB(1) DSUB(2) DSUB(3) DSUB(4) DSUB(5) DSUB(6) DSUB(7)
#undef DSUB

        {
            const double C = 0.70710678118654752440084436210485;
            double a0 = vr0 + vr4, a1 = vr1 + vr5, a2 = vr2 + vr6, a3 = vr3 + vr7;
            double d0 = vr0 - vr4, d1 = vr1 - vr5, d2 = vr2 - vr6, d3 = vr3 - vr7;
            double c0 = a0 + a2, c2 = a0 - a2, c1 = a1 + a3;
            double c3i = a3 - a1;
            double e1r = C * (d1 - d3), e1i = -C * (d1 + d3);
            vr0 = c0 + c1;   vi0 = 0.0;
            vr1 = c0 - c1;   vi1 = 0.0;
            vr2 = c2;        vi2 = c3i;
            vr3 = c2;        vi3 = -c3i;
            vr4 = d0 + e1r;  vi4 = -d2 + e1i;
            vr5 = d0 - e1r;  vi5 = -d2 - e1i;
            vr6 = d0 - e1r;  vi6 =  d2 + e1i;
            vr7 = d0 + e1r;  vi7 =  d2 - e1i;
        }

        double w1r = 1.0, w1i = 0.0;
        {
            constexpr double Cr[6] = {0.9999247018391445033, 0.9996988186962042201,
                                      0.9987954562051723927, 0.9951847266721968862,
                                      0.9807852804032304491, 0.9238795325112867561};
            constexpr double Ci[6] = {-0.0122715382857199261, -0.0245412285229122880,
                                      -0.0490676743274180143, -0.0980171403295606020,
                                      -0.1950903220161282678, -0.3826834323650897717};
#pragma unroll
            for (int j = 0; j < 6; ++j) {
                const bool on = (l >> j) & 1;
                const double mr = on ? Cr[j] : 1.0;
                const double mi = on ? Ci[j] : 0.0;
                const double nr = w1r * mr - w1i * mi;
                w1i = w1r * mi + w1i * mr;
                w1r = nr;
            }
        }

        {
            double wkr = w1r, wki = w1i;
#define DTWID(n_) { double tr_ = vr##n_ * wkr - vi##n_ * wki; \
                    vi##n_ = vr##n_ * wki + vi##n_ * wkr; vr##n_ = tr_; }
#define DWSTEP() { double nr_ = wkr * w1r - wki * w1i; \
                   wki = wkr * w1i + wki * w1r; wkr = nr_; }
            DTWID(4) DWSTEP() DTWID(2) DWSTEP() DTWID(6) DWSTEP() DTWID(1)
            DWSTEP() DTWID(5) DWSTEP() DTWID(3) DWSTEP() DTWID(7)
#undef DTWID
#undef DWSTEP
        }

        double twr, twi;
        {
            double w2r = w1r * w1r - w1i * w1i, w2i = 2.0 * w1r * w1i;
            double w4r = w2r * w2r - w2i * w2i, w4i = 2.0 * w2r * w2i;
            twr = w4r * w4r - w4i * w4i; twi = 2.0 * w4r * w4i;
        }
#define DBF(R, I, h, hi, ter, tei) { \
        double br_ = __shfl_xor(R, h); double bi_ = __shfl_xor(I, h); \
        double dr_ = hi ? (R - br_) : (R + br_); \
        double di_ = hi ? (I - bi_) : (I + bi_); \
        R = dr_ * ter - di_ * tei; I = dr_ * tei + di_ * ter; }
#define DSTG(hc) { \
        const bool hi_ = (l & hc) != 0; \
        const double ter_ = hi_ ? twr : 1.0; \
        const double tei_ = hi_ ? twi : 0.0; \
        DBF(vr0, vi0, hc, hi_, ter_, tei_) DBF(vr1, vi1, hc, hi_, ter_, tei_) \
        DBF(vr2, vi2, hc, hi_, ter_, tei_) DBF(vr3, vi3, hc, hi_, ter_, tei_) \
        DBF(vr4, vi4, hc, hi_, ter_, tei_) DBF(vr5, vi5, hc, hi_, ter_, tei_) \
        DBF(vr6, vi6, hc, hi_, ter_, tei_) DBF(vr7, vi7, hc, hi_, ter_, tei_) \
        double ntr_ = twr * twr - twi * twi; twi = 2.0 * twr * twi; twr = ntr_; }
        DSTG(32) DSTG(16) DSTG(8) DSTG(4) DSTG(2) DSTG(1)
#undef DSTG
#undef DBF

        const int k2 = (int)(__brev((unsigned)l) >> 26);
        double ps = 0.0;
        if ((l & 1) == 0) {
            const int kb = 8 * k2;
            double P;
            P = vr0 * vr0 + vi0 * vi0; ps += P; Pw[wv][0 + kb] = P;
            P = vr1 * vr1 + vi1 * vi1; ps += P; Pw[wv][4 + kb] = P;
            P = vr2 * vr2 + vi2 * vi2; ps += P; Pw[wv][2 + kb] = P;
            P = vr3 * vr3 + vi3 * vi3; ps += P; Pw[wv][6 + kb] = P;
            P = vr4 * vr4 + vi4 * vi4; ps += P; Pw[wv][1 + kb] = P;
            P = vr5 * vr5 + vi5 * vi5; ps += P; Pw[wv][5 + kb] = P;
            P = vr6 * vr6 + vi6 * vi6; ps += P; Pw[wv][3 + kb] = P;
            P = vr7 * vr7 + vi7 * vi7; ps += P; Pw[wv][7 + kb] = P;
        }
#pragma unroll
        for (int off = 1; off < 64; off <<= 1) ps += __shfl_xor(ps, off);

        {
            const int e = l >> 2, kb = l & 3;
            double acc = 0.0;
#pragma unroll 8
            for (int j = 0; j < 64; ++j) {
                int k = kb + 4 * j;
                acc += Pw[wv][k] * (double)gw[e * NFREQ + k];
            }
            acc += __shfl_xor(acc, 1);
            acc += __shfl_xor(acc, 2);
            if (kb == 0) Gs[wv][e] = acc;
        }

        if (l == 0) {
            const double sdiv  = (ps == 0.0) ? 1.0 : ps;
            const double inv_s = 1.0 / sdiv;
            double best = -1e300, best2 = -1e300;
            int i0b = 0, i1b = 0;
#pragma unroll
            for (int i = 0; i < NEXP; ++i) {
                double v = Gs[wv][i] * inv_s + (double)gb[i];
                if (v > best)       { best2 = best; i1b = i0b; best = v; i0b = i; }
                else if (v > best2) { best2 = v; i1b = i; }
            }
            const double eexp = (double)__expf((float)(best2 - best));
            const double w0 = 1.0 / (1.0 + eexp);
            const double w1 = eexp / (1.0 + eexp);
            meta[b * 4 + 0] = (float)mu;
            meta[b * 4 + 1] = (float)(w0 * sd);
            meta[b * 4 + 2] = (float)(w1 * sd);
            meta[b * 4 + 3] = (float)sd;
            eidx[b * 2 + 0] = i0b;
            eidx[b * 2 + 1] = i1b;
        }
    }
}

// ---------------- K4: per-block histogram (LDS only) ---------------------------------
__global__ __launch_bounds__(256) void k_count(const int* __restrict__ eidx,
                                               int* __restrict__ blockHist)
{
    __shared__ int h[32];
    const int t   = threadIdx.x;
    const int blk = blockIdx.x;
    if (t < 32) h[t] = 0;
    __syncthreads();
    const int b  = blk * 256 + t;
    const int e0 = eidx[2 * b];
    const int e1 = eidx[2 * b + 1];
    atomicAdd(&h[e0], 1);
    atomicAdd(&h[16 + e1], 1);
    __syncthreads();
    if (t < 32) blockHist[(t >> 4) * 512 + blk * 16 + (t & 15)] = h[t];
}

// ---------------- K5: scan hists -> counts, offs, tdesc, per-block bases -------------
__global__ void k_scan(const int* __restrict__ blockHist, int* __restrict__ counts,
                       int* __restrict__ offs, int* __restrict__ tdesc,
                       int* __restrict__ base)
{
    __shared__ int cnt[32];
    __shared__ int off_s[32];
    const int j = threadIdx.x;
    if (j < 32) {
        const int s = j >> 4, e = j & 15;
        int acc = 0;
        for (int blk = 0; blk < 32; ++blk) acc += blockHist[s * 512 + blk * 16 + e];
        cnt[j] = acc;
        counts[j] = acc;
    }
    __syncthreads();
    if (j < 2) {
        int acc = 0, tt = 0;
        for (int i = 0; i < NEXP; ++i) {
            const int c = cnt[j * 16 + i];
            off_s[j * 16 + i] = acc;
            offs[j * 16 + i]  = acc;
            acc += c;
            const int nt = (c + 63) >> 6;
            for (int k = 0; k < nt; ++k) tdesc[j * 160 + tt++] = (i << 16) | k;
        }
        for (; tt < 160; ++tt) tdesc[j * 160 + tt] = -1;
    }
    __syncthreads();
    if (j < 32) {
        const int s = j >> 4, e = j & 15;
        int run = off_s[j];
        for (int blk = 0; blk < 32; ++blk) {
            base[s * 512 + blk * 16 + e] = run;
            run += blockHist[s * 512 + blk * 16 + e];
        }
    }
}

// ---------------- K6: scatter via ballot prefix (zero atomics) -----------------------
__global__ __launch_bounds__(256) void k_scatter(const int* __restrict__ eidx,
                                                 const int* __restrict__ base,
                                                 int* __restrict__ lists)
{
    __shared__ int whist[2][4][16];
    const int t   = threadIdx.x;
    const int wv  = t >> 6, l = t & 63;
    const int blk = blockIdx.x;
    const int b   = blk * 256 + t;
    const int e0  = eidx[2 * b];
    const int e1  = eidx[2 * b + 1];
    const unsigned long long before = (1ULL << l) - 1ULL;

    unsigned long long m0 = 0, m1 = 0;
#pragma unroll
    for (int bb = 0; bb < 16; ++bb) {
        unsigned long long m = __ballot(e0 == bb);
        if (e0 == bb) m0 = m;
        if (l == 0) whist[0][wv][bb] = __popcll(m);
    }
#pragma unroll
    for (int bb = 0; bb < 16; ++bb) {
        unsigned long long m = __ballot(e1 == bb);
        if (e1 == bb) m1 = m;
        if (l == 0) whist[1][wv][bb] = __popcll(m);
    }
    __syncthreads();

    int p0 = __popcll(m0 & before);
    int p1 = __popcll(m1 & before);
    for (int w = 0; w < 4; ++w) {
        if (w < wv) {
            p0 += whist[0][w][e0];
            p1 += whist[1][w][e1];
        }
    }
    lists[base[blk * 16 + e0] + p0]                 = b;
    lists[NROWS + base[512 + blk * 16 + e1] + p1]   = b;
}

// ---------------- K7: BOTH slots, 64x64 tile, BK=32, 3-buffer ring (25 KB LDS) -------
__global__ __launch_bounds__(256, 6) void k_expert_gemm(
    const __hip_bfloat16* __restrict__ xn, const __hip_bfloat16* __restrict__ ewt,
    const float* __restrict__ eb, const float* __restrict__ meta,
    const int* __restrict__ lists, const int* __restrict__ offs,
    const int* __restrict__ counts, const int* __restrict__ tdesc,
    float* __restrict__ out, float* __restrict__ out2)
{
    const int wgid = xcd_swizzle(blockIdx.x, 3456);
    const int slot = wgid / 1728;
    const int rem  = wgid - slot * 1728;
    const int tid  = rem / 12;
    const int ct   = rem % 12;
    const int d    = tdesc[slot * 160 + tid];
    if (d < 0) return;
    const int e  = d >> 16;
    const int rt = d & 0xffff;
    const int n_e = counts[slot * NEXP + e];

    __shared__ __align__(16) __hip_bfloat16 As[3][64][32];
    __shared__ __align__(16) __hip_bfloat16 Bs[3][64][32];
    __shared__ int   rowB[64];
    __shared__ float rowMu[64];
    __shared__ float rowC[64];

    const int t  = threadIdx.x;
    const int wv = t >> 6, l = t & 63;
    const int* list = lists + slot * NROWS + offs[slot * NEXP + e];
    if (t < 64) {
        int r  = rt * 64 + t;
        int bb = (r < n_e) ? list[r] : -1;
        rowB[t]  = bb;
        rowMu[t] = (bb >= 0) ? meta[bb * 4] : 0.f;
        rowC[t]  = (bb >= 0) ? meta[bb * 4 + 1 + slot] : 0.f;
    }
    __syncthreads();

    const int srow = t >> 2, schk = t & 3;
    const int sswz = (srow >> 1) & 3;
    const int ab   = rowB[srow];
    const __hip_bfloat16* asrc =
        xn + ((ab >= 0) ? (size_t)ab * SEQ : 0) + (size_t)(schk ^ sswz) * 8;
    const int gc  = ct * 64 + srow;
    const int gcc = (gc < PRED) ? gc : (PRED - 1);
    const __hip_bfloat16* bsrc =
        ewt + ((size_t)e * PRED + gcc) * SEQ + (size_t)(schk ^ sswz) * 8;

#define STAGE(buf, koff) do {                                              \
    gload_lds16(asrc + (koff), &As[buf][srow][schk * 8]);                  \
    gload_lds16(bsrc + (koff), &Bs[buf][srow][schk * 8]);                  \
} while (0)

    f32x16 acc;
#pragma unroll
    for (int q = 0; q < 16; ++q) acc[q] = 0.f;

    const int wr = wv >> 1, wc = wv & 1;
    const int fl = l & 31, fh = l >> 5;
    const int rswz = (fl >> 1) & 3;

    STAGE(0, 0);
    STAGE(1, 32);
#pragma unroll
    for (int kt = 0; kt < 16; ++kt) {
        const int cur = kt % 3;
        if (kt < 15) asm volatile("s_waitcnt vmcnt(2)" ::: "memory");
        else         asm volatile("s_waitcnt vmcnt(0)" ::: "memory");
        __builtin_amdgcn_sched_barrier(0);
        __builtin_amdgcn_s_barrier();
        __builtin_amdgcn_sched_barrier(0);
#pragma unroll
        for (int ks = 0; ks < 2; ++ks) {
            const int cc = ((ks * 2 + fh) ^ rswz) * 8;
            const bf16x8 a = *(const bf16x8*)&As[cur][wr * 32 + fl][cc];
            const bf16x8 b = *(const bf16x8*)&Bs[cur][wc * 32 + fl][cc];
            acc = __builtin_amdgcn_mfma_f32_32x32x16_bf16(a, b, acc, 0, 0, 0);
        }
        if (kt + 2 < 16) STAGE((kt + 2) % 3, (kt + 2) * 32);
    }
#undef STAGE

    const int crow_base = 4 * fh;
    const int col = ct * 64 + wc * 32 + fl;
    const bool cok = (col < PRED);
    const float ebv = cok ? eb[e * PRED + col] : 0.f;
#pragma unroll
    for (int q = 0; q < 16; ++q) {
        const int rl = wr * 32 + (q & 3) + 8 * (q >> 2) + crow_base;
        const int bb = rowB[rl];
        if (!cok || bb < 0) continue;
        const float v = acc[q] + ebv;
        if (slot == 0) out [(size_t)bb * PRED + col] = rowMu[rl] + rowC[rl] * v;
        else           out2[(size_t)bb * PRED + col] = rowC[rl] * v;
    }
}

// ---------------- K8: merge out += out2 (vectorized) ---------------------------------
__global__ __launch_bounds__(256) void k_merge(float* __restrict__ out,
                                               const float* __restrict__ out2)
{
    const int i = blockIdx.x * 256 + threadIdx.x;
    float4 a = ((float4*)out)[i];
    const float4 b = ((const float4*)out2)[i];
    a.x += b.x; a.y += b.y; a.z += b.z; a.w += b.w;
    ((float4*)out)[i] = a;
}

// -------------------------------- launch ---------------------------------------------
extern "C" void kernel_launch(void* const* d_in, const int* in_sizes, int n_in,
                              void* d_out, int out_size, void* d_ws, size_t ws_size,
                              hipStream_t stream)
{
    const float* x  = (const float*)d_in[0];
    const float* gw = (const float*)d_in[1];
    const float* gb = (const float*)d_in[2];
    const float* ew = (const float*)d_in[3];
    const float* eb = (const float*)d_in[4];
    float* out = (float*)d_out;
    char*  ws  = (char*)d_ws;

    constexpr size_t XN_OFF   = 0;
    constexpr size_t XN_SZ    = (size_t)NROWS * SEQ * 2;
    constexpr size_t XNLO_OFF = XN_OFF + XN_SZ;
    constexpr size_t EWT_OFF  = XNLO_OFF + XN_SZ;
    constexpr size_t EWT_SZ   = (size_t)NEXP * PRED * SEQ * 2;
    constexpr size_t BTHI_OFF = EWT_OFF + EWT_SZ;
    constexpr size_t BT_SZ    = (size_t)512 * 512 * 2;
    constexpr size_t BTLO_OFF = BTHI_OFF + BT_SZ;
    constexpr size_t IOUT_OFF = BTLO_OFF + BT_SZ;
    constexpr size_t IOUT_SZ  = (size_t)NROWS * NFREQ * 4;
    constexpr size_t META_OFF = IOUT_OFF + IOUT_SZ;
    constexpr size_t META_SZ  = (size_t)NROWS * 4 * 4;
    constexpr size_t EIDX_OFF = META_OFF + META_SZ;
    constexpr size_t EIDX_SZ  = (size_t)NROWS * 2 * 4;
    constexpr size_t LIST_OFF = EIDX_OFF + EIDX_SZ;
    constexpr size_t LIST_SZ  = (size_t)2 * NROWS * 4;
    constexpr size_t CNT_OFF  = LIST_OFF + LIST_SZ;
    constexpr size_t OFFS_OFF = CNT_OFF + 144;
    constexpr size_t TDSC_OFF = OFFS_OFF + 128;
    constexpr size_t BH_OFF   = TDSC_OFF + 1280;
    constexpr size_t BASE_OFF = BH_OFF + 4096;
    constexpr size_t REDO_OFF = BASE_OFF + 4096;
    constexpr size_t OUT2_OFF = REDO_OFF + (size_t)NROWS * 4;

    __hip_bfloat16* xn   = (__hip_bfloat16*)(ws + XN_OFF);
    __hip_bfloat16* xnlo = (__hip_bfloat16*)(ws + XNLO_OFF);
    __hip_bfloat16* ewt  = (__hip_bfloat16*)(ws + EWT_OFF);
    __hip_bfloat16* bthi = (__hip_bfloat16*)(ws + BTHI_OFF);
    __hip_bfloat16* btlo = (__hip_bfloat16*)(ws + BTLO_OFF);
    float* Iout  = (float*)(ws + IOUT_OFF);
    float* meta  = (float*)(ws + META_OFF);
    int* eidx    = (int*)(ws + EIDX_OFF);
    int* lists   = (int*)(ws + LIST_OFF);
    int* counts  = (int*)(ws + CNT_OFF);
    int* nredo   = (int*)(ws + CNT_OFF + 128);
    int* offs    = (int*)(ws + OFFS_OFF);
    int* tdesc   = (int*)(ws + TDSC_OFF);
    int* bhist   = (int*)(ws + BH_OFF);
    int* base    = (int*)(ws + BASE_OFF);
    int* redo    = (int*)(ws + REDO_OFF);
    float* out2  = (float*)(ws + OUT2_OFF);

    k_preproc<<<dim3(8448), dim3(256), 0, stream>>>(ew, x, ewt, bthi, btlo,
                                                    xn, xnlo, meta, nredo);
    k_dft_gemm<<<dim3(1024), dim3(256), 0, stream>>>(xn, xnlo, bthi, btlo, Iout);
    k_gatefin<<<dim3(NROWS / 4), dim3(256), 0, stream>>>(Iout, gw, gb, meta, eidx,
                                                         redo, nredo);
    k_gate64<<<dim3(64), dim3(256), 0, stream>>>(x, gw, gb, meta, eidx, redo, nredo);
    k_count<<<dim3(32), dim3(256), 0, stream>>>(eidx, bhist);
    k_scan<<<dim3(1), dim3(64), 0, stream>>>(bhist, counts, offs, tdesc, base);
    k_scatter<<<dim3(32), dim3(256), 0, stream>>>(eidx, base, lists);
    k_expert_gemm<<<dim3(3456), dim3(256), 0, stream>>>(
        xn, ewt, eb, meta, lists, offs, counts, tdesc, out, out2);
    k_merge<<<dim3(NROWS * PRED / 1024), dim3(256), 0, stream>>>(out, out2);
}

// Round 14
// 141.389 us; speedup vs baseline: 1.0561x; 1.0561x over previous
//
#include <hip/hip_runtime.h>
#include <hip/hip_bf16.h>
#include <math.h>

#define NEXP  16
#define SEQ   512
#define PRED  720
#define NROWS 8192
#define NFREQ 256

typedef __bf16 bf16x8 __attribute__((ext_vector_type(8)));
typedef float  f32x16 __attribute__((ext_vector_type(16)));

__device__ __forceinline__ void gload_lds16(const void* g, void* l) {
    __builtin_amdgcn_global_load_lds(
        (const __attribute__((address_space(1))) unsigned int*)g,
        (__attribute__((address_space(3))) unsigned int*)l, 16, 0, 0);
}

// bijective XCD swizzle (m204)
__device__ __forceinline__ int xcd_swizzle(int bid, int nwg) {
    const int q = nwg >> 3, r = nwg & 7;
    const int xcd = bid & 7, off = bid >> 3;
    return (xcd < r ? xcd * (q + 1) : r * (q + 1) + (xcd - r) * q) + off;
}

// ---------------- K0: fused preprocessing (build_dft | transpose_ew | stats) ---------
__global__ __launch_bounds__(256) void k_preproc(const float* __restrict__ ew,
                                                 const float* __restrict__ x,
                                                 __hip_bfloat16* __restrict__ ewt,
                                                 __hip_bfloat16* __restrict__ bthi,
                                                 __hip_bfloat16* __restrict__ btlo,
                                                 __hip_bfloat16* __restrict__ xn,
                                                 __hip_bfloat16* __restrict__ xnlo,
                                                 float* __restrict__ meta,
                                                 int* __restrict__ nredo)
{
    const int bid = blockIdx.x;
    const int t   = threadIdx.x;

    if (bid < 512) {
        if (bid == 0 && t == 0) *nredo = 0;
        const int tid  = bid * 256 + t;
        const int f    = tid >> 9;
        const int lidx = tid & 511;
        const int m    = (f * lidx) & 511;

        constexpr double Cj[9] = {0.9999247018391445033, 0.9996988186962042201,
                                  0.9987954562051723927, 0.9951847266721968862,
                                  0.9807852804032304491, 0.9238795325112867561,
                                  0.7071067811865475244, 0.0, -1.0};
        constexpr double Sj[9] = {0.0122715382857199261, 0.0245412285229122880,
                                  0.0490676743274180143, 0.0980171403295606020,
                                  0.1950903220161282678, 0.3826834323650897717,
                                  0.7071067811865475244, 1.0, 0.0};
        double cr = 1.0, ci = 0.0;
#pragma unroll
        for (int j = 0; j < 9; ++j) {
            const bool on = (m >> j) & 1;
            const double mr = on ? Cj[j] : 1.0;
            const double mi = on ? Sj[j] : 0.0;
            const double nr = cr * mr - ci * mi;
            ci = cr * mi + ci * mr;
            cr = nr;
        }
        const size_t c0 = (size_t)(2 * f) * 512 + lidx;
        const size_t c1 = (size_t)(2 * f + 1) * 512 + lidx;
        {
            __hip_bfloat16 h = __float2bfloat16((float)cr);
            float hif = __bfloat162float(h);
            bthi[c0] = h;
            btlo[c0] = __float2bfloat16((float)(cr - (double)hif));
        }
        {
            __hip_bfloat16 h = __float2bfloat16((float)ci);
            float hif = __bfloat162float(h);
            bthi[c1] = h;
            btlo[c1] = __float2bfloat16((float)(ci - (double)hif));
        }
        return;
    }

    if (bid < 6400) {
        __shared__ float tile[32][33];
        const int rel = bid - 512;
        const int e   = rel / 368;
        const int rem = rel % 368;
        const int p0  = (rem % 23) * 32;
        const int l0  = (rem / 23) * 32;
        const int tx  = t & 31;
        const int ty  = t >> 5;
        const float* src = ew + (size_t)e * SEQ * PRED;
#pragma unroll
        for (int i = 0; i < 4; ++i) {
            int l = l0 + ty + i * 8;
            int p = p0 + tx;
            tile[ty + i * 8][tx] = (p < PRED) ? src[(size_t)l * PRED + p] : 0.f;
        }
        __syncthreads();
        __hip_bfloat16* dst = ewt + (size_t)e * PRED * SEQ;
#pragma unroll
        for (int i = 0; i < 4; ++i) {
            int p = p0 + ty + i * 8;
            int l = l0 + tx;
            if (p < PRED) dst[(size_t)p * SEQ + l] = __float2bfloat16(tile[tx][ty + i * 8]);
        }
        return;
    }

    {
        const int wv = t >> 6, l = t & 63;
        const int b  = (bid - 6400) * 4 + wv;
        const float* xr = x + (size_t)b * SEQ;

        const float4 v0 = *(const float4*)(xr + l * 8);
        const float4 v1 = *(const float4*)(xr + l * 8 + 4);
        const double d0 = v0.x, d1 = v0.y, d2 = v0.z, d3 = v0.w;
        const double d4 = v1.x, d5 = v1.y, d6 = v1.z, d7 = v1.w;

        double s1 = ((d0 + d1) + (d2 + d3)) + ((d4 + d5) + (d6 + d7));
        double s2 = ((d0 * d0 + d1 * d1) + (d2 * d2 + d3 * d3)) +
                    ((d4 * d4 + d5 * d5) + (d6 * d6 + d7 * d7));
#pragma unroll
        for (int off = 1; off < 64; off <<= 1) {
            s1 += __shfl_xor(s1, off);
            s2 += __shfl_xor(s2, off);
        }
        const double mu = s1 * (1.0 / 512.0);
        double var = s2 * (1.0 / 512.0) - mu * mu;
        if (var < 0.0) var = 0.0;
        const double sd = sqrt(var) + 1e-5, inv = 1.0 / sd;

        unsigned int hw[4], lw[4];
#define CONV(j, dj)                                                         \
        {                                                                   \
            double xnd = (dj - mu) * inv;                                   \
            __hip_bfloat16 h = __float2bfloat16((float)xnd);                \
            float hif = __bfloat162float(h);                                \
            __hip_bfloat16 lo = __float2bfloat16((float)(xnd - (double)hif)); \
            unsigned int hb = *(unsigned short*)&h;                         \
            unsigned int lb = *(unsigned short*)&lo;                        \
            if ((j & 1) == 0) { hw[j >> 1] = hb; lw[j >> 1] = lb; }         \
            else { hw[j >> 1] |= hb << 16; lw[j >> 1] |= lb << 16; }        \
        }
        CONV(0, d0) CONV(1, d1) CONV(2, d2) CONV(3, d3)
        CONV(4, d4) CONV(5, d5) CONV(6, d6) CONV(7, d7)
#undef CONV
        *(uint4*)(xn   + (size_t)b * SEQ + l * 8) = uint4{hw[0], hw[1], hw[2], hw[3]};
        *(uint4*)(xnlo + (size_t)b * SEQ + l * 8) = uint4{lw[0], lw[1], lw[2], lw[3]};

        if (l == 0) {
            meta[b * 4 + 0] = (float)mu;
            meta[b * 4 + 3] = (float)sd;
        }
    }
}

// ---------------- K1: DFT as GEMM, 64x128 tile, BK=64, stage->MFMA->drain->barrier ---
__global__ __launch_bounds__(256, 3) void k_dft_gemm(
    const __hip_bfloat16* __restrict__ xn, const __hip_bfloat16* __restrict__ xnlo,
    const __hip_bfloat16* __restrict__ bthi, const __hip_bfloat16* __restrict__ btlo,
    float* __restrict__ Iout)
{
    const int wgid = xcd_swizzle(blockIdx.x, 512);
    const int rt = wgid >> 2;     // 0..127 (64 rows)
    const int ct = wgid & 3;      // 0..3   (128 cols)

    __shared__ __align__(16) __hip_bfloat16 As[2][64][64];
    __shared__ __align__(16) __hip_bfloat16 Bs[2][128][64];

    const int t  = threadIdx.x;
    const int wv = t >> 6, l = t & 63;

    size_t aoff[2], boff[4];
    int arow[2], achk[2], brow[4], bchk[4];
#pragma unroll
    for (int i = 0; i < 2; ++i) {
        const int idx = i * 256 + t;
        const int row = idx >> 3, chk = idx & 7;
        const int swz = (row & 7) ^ ((row & 8) >> 1);
        arow[i] = row; achk[i] = chk;
        aoff[i] = (size_t)(rt * 64 + row) * SEQ + (size_t)(chk ^ swz) * 8;
    }
#pragma unroll
    for (int i = 0; i < 4; ++i) {
        const int idx = i * 256 + t;
        const int row = idx >> 3, chk = idx & 7;
        const int swz = (row & 7) ^ ((row & 8) >> 1);
        brow[i] = row; bchk[i] = chk;
        boff[i] = (size_t)(ct * 128 + row) * SEQ + (size_t)(chk ^ swz) * 8;
    }

#define DSTAGE(buf, kk) do {                                                   \
    const int pass_ = (kk) >> 3;                                               \
    const int koff_ = ((kk) & 7) * 64;                                         \
    const __hip_bfloat16* ap_ = (pass_ == 1) ? xnlo : xn;                      \
    const __hip_bfloat16* bp_ = (pass_ == 2) ? btlo : bthi;                    \
    _Pragma("unroll")                                                          \
    for (int i_ = 0; i_ < 2; ++i_)                                             \
        gload_lds16(ap_ + aoff[i_] + koff_, &As[buf][arow[i_]][achk[i_] * 8]); \
    _Pragma("unroll")                                                          \
    for (int i_ = 0; i_ < 4; ++i_)                                             \
        gload_lds16(bp_ + boff[i_] + koff_, &Bs[buf][brow[i_]][bchk[i_] * 8]); \
} while (0)

    f32x16 acc[2];
#pragma unroll
    for (int ni = 0; ni < 2; ++ni)
#pragma unroll
        for (int q = 0; q < 16; ++q) acc[ni][q] = 0.f;

    const int wr = wv >> 1, wc = wv & 1;
    const int fl = l & 31, fh = l >> 5;
    const int rswz = (fl & 7) ^ ((fl & 8) >> 1);

    DSTAGE(0, 0);
    asm volatile("s_waitcnt vmcnt(0)" ::: "memory");
    __builtin_amdgcn_s_barrier();
#pragma unroll
    for (int kt = 0; kt < 24; ++kt) {
        const int cur = kt & 1;
        if (kt < 23) DSTAGE(cur ^ 1, kt + 1);     // issue next tile's loads FIRST
        __builtin_amdgcn_sched_barrier(0);
        __builtin_amdgcn_s_setprio(1);
#pragma unroll
        for (int ks = 0; ks < 4; ++ks) {
            const int cc = ((ks * 2 + fh) ^ rswz) * 8;
            const bf16x8 a  = *(const bf16x8*)&As[cur][wr * 32 + fl][cc];
            const bf16x8 b0 = *(const bf16x8*)&Bs[cur][wc * 64 + fl][cc];
            const bf16x8 b1 = *(const bf16x8*)&Bs[cur][wc * 64 + 32 + fl][cc];
            acc[0] = __builtin_amdgcn_mfma_f32_32x32x16_bf16(a, b0, acc[0], 0, 0, 0);
            acc[1] = __builtin_amdgcn_mfma_f32_32x32x16_bf16(a, b1, acc[1], 0, 0, 0);
        }
        __builtin_amdgcn_s_setprio(0);
        __builtin_amdgcn_sched_barrier(0);
        asm volatile("s_waitcnt vmcnt(0)" ::: "memory");   // drain covered by MFMA phase
        __builtin_amdgcn_s_barrier();                       // single barrier per K-step
    }
#undef DSTAGE

    const int crow_base = 4 * fh;
#pragma unroll
    for (int ni = 0; ni < 2; ++ni) {
        const int col = ct * 128 + wc * 64 + ni * 32 + fl;
#pragma unroll
        for (int q = 0; q < 16; ++q) {
            const float v = acc[ni][q];
            const float w = __shfl_xor(v, 1);
            if ((fl & 1) == 0) {
                const int rl = wr * 32 + (q & 3) + 8 * (q >> 2) + crow_base;
                Iout[(size_t)(rt * 64 + rl) * NFREQ + (col >> 1)] = v * v + w * w;
            }
        }
    }
}

// ---------------- K2: gate finalize (no contended atomics) ---------------------------
__global__ __launch_bounds__(256) void k_gatefin(const float* __restrict__ Iout,
                                                 const float* __restrict__ gw,
                                                 const float* __restrict__ gb,
                                                 float* __restrict__ meta,
                                                 int* __restrict__ eidx,
                                                 int* __restrict__ redo,
                                                 int* __restrict__ nredo)
{
    __shared__ float gws[NEXP * 257];
    __shared__ float Pw[4][256];
    __shared__ float Gs[4][16];

    const int t  = threadIdx.x;
    const int wv = t >> 6, l = t & 63;
    const int b  = blockIdx.x * 4 + wv;

    for (int i = t; i < NEXP * NFREQ; i += 256)
        gws[(i >> 8) * 257 + (i & 255)] = gw[i];
    __syncthreads();

    const float* Ir = Iout + (size_t)b * NFREQ;
    const float i0 = Ir[l], i1 = Ir[64 + l], i2 = Ir[128 + l], i3 = Ir[192 + l];
    Pw[wv][l] = i0; Pw[wv][64 + l] = i1; Pw[wv][128 + l] = i2; Pw[wv][192 + l] = i3;
    float ps = (i0 + i1) + (i2 + i3);
#pragma unroll
    for (int off = 1; off < 64; off <<= 1) ps += __shfl_xor(ps, off);

    const int e = l >> 2, kb = l & 3;
    float acc = 0.f;
#pragma unroll 8
    for (int j = 0; j < 64; ++j) {
        const int k = kb + 4 * j;
        acc += Pw[wv][k] * gws[e * 257 + k];
    }
    acc += __shfl_xor(acc, 1);
    acc += __shfl_xor(acc, 2);
    if (kb == 0) Gs[wv][e] = acc;

    if (l == 0) {
        const float sdiv  = (ps == 0.f) ? 1.f : ps;
        const float inv_s = 1.f / sdiv;
        float b1 = -1e30f, b2 = -1e30f, b3 = -1e30f;
        int i1b = 0, i2b = 0;
#pragma unroll
        for (int i = 0; i < NEXP; ++i) {
            float v = Gs[wv][i] * inv_s + gb[i];
            if (v > b1)      { b3 = b2; b2 = b1; i2b = i1b; b1 = v; i1b = i; }
            else if (v > b2) { b3 = b2; b2 = v; i2b = i; }
            else if (v > b3) { b3 = v; }
        }
        if (b2 - b3 < 1e-4f * fmaxf(1.f, fabsf(b1))) {
            const int r = atomicAdd(nredo, 1);
            redo[r] = b;
        } else {
            const float sd = meta[b * 4 + 3];
            const float ee = __expf(b2 - b1);
            const float w0 = 1.f / (1.f + ee);
            const float w1 = ee / (1.f + ee);
            meta[b * 4 + 1] = w0 * sd;
            meta[b * 4 + 2] = w1 * sd;
            eidx[b * 2 + 0] = i1b;
            eidx[b * 2 + 1] = i2b;
        }
    }
}

// ---------------- K3: fp64 recheck of ambiguous rows ---------------------------------
__global__ __launch_bounds__(256, 4) void k_gate64(const float* __restrict__ x,
                                                   const float* __restrict__ gw,
                                                   const float* __restrict__ gb,
                                                   float* __restrict__ meta,
                                                   int* __restrict__ eidx,
                                                   const int* __restrict__ redo,
                                                   const int* __restrict__ nredo)
{
    __shared__ double Pw[4][256];
    __shared__ double Gs[4][16];

    const int t  = threadIdx.x;
    const int wv = t >> 6, l = t & 63;
    const int n  = *nredo;

    for (int it = blockIdx.x * 4 + wv; it < n; it += gridDim.x * 4) {
        const int b = redo[it];
        const float* xr = x + (size_t)b * SEQ;

        double s1 = 0.0, s2 = 0.0;
#define DLOADV(n_) double vr##n_ = (double)xr[64 * n_ + l]; s1 += vr##n_; s2 += vr##n_ * vr##n_;
        DLOADV(0) DLOADV(1) DLOADV(2) DLOADV(3) DLOADV(4) DLOADV(5) DLOADV(6) DLOADV(7)
#undef DLOADV
        double vi0, vi1, vi2, vi3, vi4, vi5, vi6, vi7;

#pragma unroll
        for (int off = 1; off < 64; off <<= 1) {
            s1 += __shfl_xor(s1, off);
            s2 += __shfl_xor(s2, off);
        }
        const double mu = s1 * (1.0 / 512.0);
        double var = s2 * (1.0 / 512.0) - mu * mu;
        if (var < 0.0) var = 0.0;
        const double sd = sqrt(var) + 1e-5;

#define DSUB(n_) vr##n_ -= mu;
        DSUB(0) DSUB(1) DSUB(2) DSUB(3) DSUB(4) DSUB(5) DSUB(6) DSUB(7)
#undef DSUB

        {
            const double C = 0.70710678118654752440084436210485;
            double a0 = vr0 + vr4, a1 = vr1 + vr5, a2 = vr2 + vr6, a3 = vr3 + vr7;
            double d0 = vr0 - vr4, d1 = vr1 - vr5, d2 = vr2 - vr6, d3 = vr3 - vr7;
            double c0 = a0 + a2, c2 = a0 - a2, c1 = a1 + a3;
            double c3i = a3 - a1;
            double e1r = C * (d1 - d3), e1i = -C * (d1 + d3);
            vr0 = c0 + c1;   vi0 = 0.0;
            vr1 = c0 - c1;   vi1 = 0.0;
            vr2 = c2;        vi2 = c3i;
            vr3 = c2;        vi3 = -c3i;
            vr4 = d0 + e1r;  vi4 = -d2 + e1i;
            vr5 = d0 - e1r;  vi5 = -d2 - e1i;
            vr6 = d0 - e1r;  vi6 =  d2 + e1i;
            vr7 = d0 + e1r;  vi7 =  d2 - e1i;
        }

        double w1r = 1.0, w1i = 0.0;
        {
            constexpr double Cr[6] = {0.9999247018391445033, 0.9996988186962042201,
                                      0.9987954562051723927, 0.9951847266721968862,
                                      0.9807852804032304491, 0.9238795325112867561};
            constexpr double Ci[6] = {-0.0122715382857199261, -0.0245412285229122880,
                                      -0.0490676743274180143, -0.0980171403295606020,
                                      -0.1950903220161282678, -0.3826834323650897717};
#pragma unroll
            for (int j = 0; j < 6; ++j) {
                const bool on = (l >> j) & 1;
                const double mr = on ? Cr[j] : 1.0;
                const double mi = on ? Ci[j] : 0.0;
                const double nr = w1r * mr - w1i * mi;
                w1i = w1r * mi + w1i * mr;
                w1r = nr;
            }
        }

        {
            double wkr = w1r, wki = w1i;
#define DTWID(n_) { double tr_ = vr##n_ * wkr - vi##n_ * wki; \
                    vi##n_ = vr##n_ * wki + vi##n_ * wkr; vr##n_ = tr_; }
#define DWSTEP() { double nr_ = wkr * w1r - wki * w1i; \
                   wki = wkr * w1i + wki * w1r; wkr = nr_; }
            DTWID(4) DWSTEP() DTWID(2) DWSTEP() DTWID(6) DWSTEP() DTWID(1)
            DWSTEP() DTWID(5) DWSTEP() DTWID(3) DWSTEP() DTWID(7)
#undef DTWID
#undef DWSTEP
        }

        double twr, twi;
        {
            double w2r = w1r * w1r - w1i * w1i, w2i = 2.0 * w1r * w1i;
            double w4r = w2r * w2r - w2i * w2i, w4i = 2.0 * w2r * w2i;
            twr = w4r * w4r - w4i * w4i; twi = 2.0 * w4r * w4i;
        }
#define DBF(R, I, h, hi, ter, tei) { \
        double br_ = __shfl_xor(R, h); double bi_ = __shfl_xor(I, h); \
        double dr_ = hi ? (R - br_) : (R + br_); \
        double di_ = hi ? (I - bi_) : (I + bi_); \
        R = dr_ * ter - di_ * tei; I = dr_ * tei + di_ * ter; }
#define DSTG(hc) { \
        const bool hi_ = (l & hc) != 0; \
        const double ter_ = hi_ ? twr : 1.0; \
        const double tei_ = hi_ ? twi : 0.0; \
        DBF(vr0, vi0, hc, hi_, ter_, tei_) DBF(vr1, vi1, hc, hi_, ter_, tei_) \
        DBF(vr2, vi2, hc, hi_, ter_, tei_) DBF(vr3, vi3, hc, hi_, ter_, tei_) \
        DBF(vr4, vi4, hc, hi_, ter_, tei_) DBF(vr5, vi5, hc, hi_, ter_, tei_) \
        DBF(vr6, vi6, hc, hi_, ter_, tei_) DBF(vr7, vi7, hc, hi_, ter_, tei_) \
        double ntr_ = twr * twr - twi * twi; twi = 2.0 * twr * twi; twr = ntr_; }
        DSTG(32) DSTG(16) DSTG(8) DSTG(4) DSTG(2) DSTG(1)
#undef DSTG
#undef DBF

        const int k2 = (int)(__brev((unsigned)l) >> 26);
        double ps = 0.0;
        if ((l & 1) == 0) {
            const int kb = 8 * k2;
            double P;
            P = vr0 * vr0 + vi0 * vi0; ps += P; Pw[wv][0 + kb] = P;
            P = vr1 * vr1 + vi1 * vi1; ps += P; Pw[wv][4 + kb] = P;
            P = vr2 * vr2 + vi2 * vi2; ps += P; Pw[wv][2 + kb] = P;
            P = vr3 * vr3 + vi3 * vi3; ps += P; Pw[wv][6 + kb] = P;
            P = vr4 * vr4 + vi4 * vi4; ps += P; Pw[wv][1 + kb] = P;
            P = vr5 * vr5 + vi5 * vi5; ps += P; Pw[wv][5 + kb] = P;
            P = vr6 * vr6 + vi6 * vi6; ps += P; Pw[wv][3 + kb] = P;
            P = vr7 * vr7 + vi7 * vi7; ps += P; Pw[wv][7 + kb] = P;
        }
#pragma unroll
        for (int off = 1; off < 64; off <<= 1) ps += __shfl_xor(ps, off);

        {
            const int e = l >> 2, kb = l & 3;
            double acc = 0.0;
#pragma unroll 8
            for (int j = 0; j < 64; ++j) {
                int k = kb + 4 * j;
                acc += Pw[wv][k] * (double)gw[e * NFREQ + k];
            }
            acc += __shfl_xor(acc, 1);
            acc += __shfl_xor(acc, 2);
            if (kb == 0) Gs[wv][e] = acc;
        }

        if (l == 0) {
            const double sdiv  = (ps == 0.0) ? 1.0 : ps;
            const double inv_s = 1.0 / sdiv;
            double best = -1e300, best2 = -1e300;
            int i0b = 0, i1b = 0;
#pragma unroll
            for (int i = 0; i < NEXP; ++i) {
                double v = Gs[wv][i] * inv_s + (double)gb[i];
                if (v > best)       { best2 = best; i1b = i0b; best = v; i0b = i; }
                else if (v > best2) { best2 = v; i1b = i; }
            }
            const double eexp = (double)__expf((float)(best2 - best));
            const double w0 = 1.0 / (1.0 + eexp);
            const double w1 = eexp / (1.0 + eexp);
            meta[b * 4 + 0] = (float)mu;
            meta[b * 4 + 1] = (float)(w0 * sd);
            meta[b * 4 + 2] = (float)(w1 * sd);
            meta[b * 4 + 3] = (float)sd;
            eidx[b * 2 + 0] = i0b;
            eidx[b * 2 + 1] = i1b;
        }
    }
}

// ---------------- K4: per-block histogram (LDS only) ---------------------------------
__global__ __launch_bounds__(256) void k_count(const int* __restrict__ eidx,
                                               int* __restrict__ blockHist)
{
    __shared__ int h[32];
    const int t   = threadIdx.x;
    const int blk = blockIdx.x;
    if (t < 32) h[t] = 0;
    __syncthreads();
    const int b  = blk * 256 + t;
    const int e0 = eidx[2 * b];
    const int e1 = eidx[2 * b + 1];
    atomicAdd(&h[e0], 1);
    atomicAdd(&h[16 + e1], 1);
    __syncthreads();
    if (t < 32) blockHist[(t >> 4) * 512 + blk * 16 + (t & 15)] = h[t];
}

// ---------------- K5: scan hists -> counts, offs, tdesc, per-block bases -------------
__global__ void k_scan(const int* __restrict__ blockHist, int* __restrict__ counts,
                       int* __restrict__ offs, int* __restrict__ tdesc,
                       int* __restrict__ base)
{
    __shared__ int cnt[32];
    __shared__ int off_s[32];
    const int j = threadIdx.x;
    if (j < 32) {
        const int s = j >> 4, e = j & 15;
        int acc = 0;
        for (int blk = 0; blk < 32; ++blk) acc += blockHist[s * 512 + blk * 16 + e];
        cnt[j] = acc;
        counts[j] = acc;
    }
    __syncthreads();
    if (j < 2) {
        int acc = 0, tt = 0;
        for (int i = 0; i < NEXP; ++i) {
            const int c = cnt[j * 16 + i];
            off_s[j * 16 + i] = acc;
            offs[j * 16 + i]  = acc;
            acc += c;
            const int nt = (c + 63) >> 6;
            for (int k = 0; k < nt; ++k) tdesc[j * 160 + tt++] = (i << 16) | k;
        }
        for (; tt < 160; ++tt) tdesc[j * 160 + tt] = -1;
    }
    __syncthreads();
    if (j < 32) {
        const int s = j >> 4, e = j & 15;
        int run = off_s[j];
        for (int blk = 0; blk < 32; ++blk) {
            base[s * 512 + blk * 16 + e] = run;
            run += blockHist[s * 512 + blk * 16 + e];
        }
    }
}

// ---------------- K6: scatter via ballot prefix (zero atomics) -----------------------
__global__ __launch_bounds__(256) void k_scatter(const int* __restrict__ eidx,
                                                 const int* __restrict__ base,
                                                 int* __restrict__ lists)
{
    __shared__ int whist[2][4][16];
    const int t   = threadIdx.x;
    const int wv  = t >> 6, l = t & 63;
    const int blk = blockIdx.x;
    const int b   = blk * 256 + t;
    const int e0  = eidx[2 * b];
    const int e1  = eidx[2 * b + 1];
    const unsigned long long before = (1ULL << l) - 1ULL;

    unsigned long long m0 = 0, m1 = 0;
#pragma unroll
    for (int bb = 0; bb < 16; ++bb) {
        unsigned long long m = __ballot(e0 == bb);
        if (e0 == bb) m0 = m;
        if (l == 0) whist[0][wv][bb] = __popcll(m);
    }
#pragma unroll
    for (int bb = 0; bb < 16; ++bb) {
        unsigned long long m = __ballot(e1 == bb);
        if (e1 == bb) m1 = m;
        if (l == 0) whist[1][wv][bb] = __popcll(m);
    }
    __syncthreads();

    int p0 = __popcll(m0 & before);
    int p1 = __popcll(m1 & before);
    for (int w = 0; w < 4; ++w) {
        if (w < wv) {
            p0 += whist[0][w][e0];
            p1 += whist[1][w][e1];
        }
    }
    lists[base[blk * 16 + e0] + p0]                 = b;
    lists[NROWS + base[512 + blk * 16 + e1] + p1]   = b;
}

// ---------------- K7: BOTH slots, 64x128 tile, BK=64, stage->MFMA->drain->barrier ----
__global__ __launch_bounds__(256, 3) void k_expert_gemm(
    const __hip_bfloat16* __restrict__ xn, const __hip_bfloat16* __restrict__ ewt,
    const float* __restrict__ eb, const float* __restrict__ meta,
    const int* __restrict__ lists, const int* __restrict__ offs,
    const int* __restrict__ counts, const int* __restrict__ tdesc,
    float* __restrict__ out, float* __restrict__ out2)
{
    const int wgid = xcd_swizzle(blockIdx.x, 1920);
    const int slot = wgid / 960;
    const int rem  = wgid - slot * 960;
    const int tid  = rem / 6;       // 0..159 (64-row tiles)
    const int ct   = rem % 6;       // 128-col tiles
    const int d    = tdesc[slot * 160 + tid];
    if (d < 0) return;
    const int e  = d >> 16;
    const int rt = d & 0xffff;
    const int n_e = counts[slot * NEXP + e];

    __shared__ __align__(16) __hip_bfloat16 As[2][64][64];
    __shared__ __align__(16) __hip_bfloat16 Bs[2][128][64];
    __shared__ int   rowB[64];
    __shared__ float rowMu[64];
    __shared__ float rowC[64];

    const int t  = threadIdx.x;
    const int wv = t >> 6, l = t & 63;
    const int* list = lists + slot * NROWS + offs[slot * NEXP + e];
    if (t < 64) {
        int r  = rt * 64 + t;
        int bb = (r < n_e) ? list[r] : -1;
        rowB[t]  = bb;
        rowMu[t] = (bb >= 0) ? meta[bb * 4] : 0.f;
        rowC[t]  = (bb >= 0) ? meta[bb * 4 + 1 + slot] : 0.f;
    }
    __syncthreads();

    const __hip_bfloat16* asrc[2];
    const __hip_bfloat16* bsrc[4];
    int arow[2], achk[2], brow[4], bchk[4];
#pragma unroll
    for (int i = 0; i < 2; ++i) {
        const int idx = i * 256 + t;
        const int row = idx >> 3, chk = idx & 7;
        const int swz = (row & 7) ^ ((row & 8) >> 1);
        arow[i] = row; achk[i] = chk;
        const int ab = rowB[row];
        asrc[i] = xn + ((ab >= 0) ? (size_t)ab * SEQ : 0) + (size_t)(chk ^ swz) * 8;
    }
#pragma unroll
    for (int i = 0; i < 4; ++i) {
        const int idx = i * 256 + t;
        const int row = idx >> 3, chk = idx & 7;
        const int swz = (row & 7) ^ ((row & 8) >> 1);
        brow[i] = row; bchk[i] = chk;
        const int gc  = ct * 128 + row;
        const int gcc = (gc < PRED) ? gc : (PRED - 1);
        bsrc[i] = ewt + ((size_t)e * PRED + gcc) * SEQ + (size_t)(chk ^ swz) * 8;
    }

#define STAGE(buf, koff) do {                                                  \
    _Pragma("unroll")                                                          \
    for (int i_ = 0; i_ < 2; ++i_)                                             \
        gload_lds16(asrc[i_] + (koff), &As[buf][arow[i_]][achk[i_] * 8]);      \
    _Pragma("unroll")                                                          \
    for (int i_ = 0; i_ < 4; ++i_)                                             \
        gload_lds16(bsrc[i_] + (koff), &Bs[buf][brow[i_]][bchk[i_] * 8]);      \
} while (0)

    f32x16 acc[2];
#pragma unroll
    for (int ni = 0; ni < 2; ++ni)
#pragma unroll
        for (int q = 0; q < 16; ++q) acc[ni][q] = 0.f;

    const int wr = wv >> 1, wc = wv & 1;
    const int fl = l & 31, fh = l >> 5;
    const int rswz = (fl & 7) ^ ((fl & 8) >> 1);

    STAGE(0, 0);
    asm volatile("s_waitcnt vmcnt(0)" ::: "memory");
    __builtin_amdgcn_s_barrier();
#pragma unroll
    for (int kt = 0; kt < 8; ++kt) {
        const int cur = kt & 1;
        if (kt < 7) STAGE(cur ^ 1, (kt + 1) * 64);   // issue next tile's loads FIRST
        __builtin_amdgcn_sched_barrier(0);
        __builtin_amdgcn_s_setprio(1);
#pragma unroll
        for (int ks = 0; ks < 4; ++ks) {
            const int cc = ((ks * 2 + fh) ^ rswz) * 8;
            const bf16x8 a  = *(const bf16x8*)&As[cur][wr * 32 + fl][cc];
            const bf16x8 b0 = *(const bf16x8*)&Bs[cur][wc * 64 + fl][cc];
            const bf16x8 b1 = *(const bf16x8*)&Bs[cur][wc * 64 + 32 + fl][cc];
            acc[0] = __builtin_amdgcn_mfma_f32_32x32x16_bf16(a, b0, acc[0], 0, 0, 0);
            acc[1] = __builtin_amdgcn_mfma_f32_32x32x16_bf16(a, b1, acc[1], 0, 0, 0);
        }
        __builtin_amdgcn_s_setprio(0);
        __builtin_amdgcn_sched_barrier(0);
        asm volatile("s_waitcnt vmcnt(0)" ::: "memory");  // drain covered by MFMA phase
        __builtin_amdgcn_s_barrier();                      // single barrier per K-step
    }
#undef STAGE

    const int crow_base = 4 * fh;
#pragma unroll
    for (int ni = 0; ni < 2; ++ni) {
        const int col = ct * 128 + wc * 64 + ni * 32 + fl;
        const bool cok = (col < PRED);
        const float ebv = cok ? eb[e * PRED + col] : 0.f;
#pragma unroll
        for (int q = 0; q < 16; ++q) {
            const int rl = wr * 32 + (q & 3) + 8 * (q >> 2) + crow_base;
            const int bb = rowB[rl];
            if (!cok || bb < 0) continue;
            const float v = acc[ni][q] + ebv;
            if (slot == 0) out [(size_t)bb * PRED + col] = rowMu[rl] + rowC[rl] * v;
            else           out2[(size_t)bb * PRED + col] = rowC[rl] * v;
        }
    }
}

// ---------------- K8: merge out += out2 (vectorized) ---------------------------------
__global__ __launch_bounds__(256) void k_merge(float* __restrict__ out,
                                               const float* __restrict__ out2)
{
    const int i = blockIdx.x * 256 + threadIdx.x;
    float4 a = ((float4*)out)[i];
    const float4 b = ((const float4*)out2)[i];
    a.x += b.x; a.y += b.y; a.z += b.z; a.w += b.w;
    ((float4*)out)[i] = a;
}

// -------------------------------- launch ---------------------------------------------
extern "C" void kernel_launch(void* const* d_in, const int* in_sizes, int n_in,
                              void* d_out, int out_size, void* d_ws, size_t ws_size,
                              hipStream_t stream)
{
    const float* x  = (const float*)d_in[0];
    const float* gw = (const float*)d_in[1];
    const float* gb = (const float*)d_in[2];
    const float* ew = (const float*)d_in[3];
    const float* eb = (const float*)d_in[4];
    float* out = (float*)d_out;
    char*  ws  = (char*)d_ws;

    constexpr size_t XN_OFF   = 0;
    constexpr size_t XN_SZ    = (size_t)NROWS * SEQ * 2;
    constexpr size_t XNLO_OFF = XN_OFF + XN_SZ;
    constexpr size_t EWT_OFF  = XNLO_OFF + XN_SZ;
    constexpr size_t EWT_SZ   = (size_t)NEXP * PRED * SEQ * 2;
    constexpr size_t BTHI_OFF = EWT_OFF + EWT_SZ;
    constexpr size_t BT_SZ    = (size_t)512 * 512 * 2;
    constexpr size_t BTLO_OFF = BTHI_OFF + BT_SZ;
    constexpr size_t IOUT_OFF = BTLO_OFF + BT_SZ;
    constexpr size_t IOUT_SZ  = (size_t)NROWS * NFREQ * 4;
    constexpr size_t META_OFF = IOUT_OFF + IOUT_SZ;
    constexpr size_t META_SZ  = (size_t)NROWS * 4 * 4;
    constexpr size_t EIDX_OFF = META_OFF + META_SZ;
    constexpr size_t EIDX_SZ  = (size_t)NROWS * 2 * 4;
    constexpr size_t LIST_OFF = EIDX_OFF + EIDX_SZ;
    constexpr size_t LIST_SZ  = (size_t)2 * NROWS * 4;
    constexpr size_t CNT_OFF  = LIST_OFF + LIST_SZ;
    constexpr size_t OFFS_OFF = CNT_OFF + 144;
    constexpr size_t TDSC_OFF = OFFS_OFF + 128;
    constexpr size_t BH_OFF   = TDSC_OFF + 1280;
    constexpr size_t BASE_OFF = BH_OFF + 4096;
    constexpr size_t REDO_OFF = BASE_OFF + 4096;
    constexpr size_t OUT2_OFF = REDO_OFF + (size_t)NROWS * 4;

    __hip_bfloat16* xn   = (__hip_bfloat16*)(ws + XN_OFF);
    __hip_bfloat16* xnlo = (__hip_bfloat16*)(ws + XNLO_OFF);
    __hip_bfloat16* ewt  = (__hip_bfloat16*)(ws + EWT_OFF);
    __hip_bfloat16* bthi = (__hip_bfloat16*)(ws + BTHI_OFF);
    __hip_bfloat16* btlo = (__hip_bfloat16*)(ws + BTLO_OFF);
    float* Iout  = (float*)(ws + IOUT_OFF);
    float* meta  = (float*)(ws + META_OFF);
    int* eidx    = (int*)(ws + EIDX_OFF);
    int* lists   = (int*)(ws + LIST_OFF);
    int* counts  = (int*)(ws + CNT_OFF);
    int* nredo   = (int*)(ws + CNT_OFF + 128);
    int* offs    = (int*)(ws + OFFS_OFF);
    int* tdesc   = (int*)(ws + TDSC_OFF);
    int* bhist   = (int*)(ws + BH_OFF);
    int* base    = (int*)(ws + BASE_OFF);
    int* redo    = (int*)(ws + REDO_OFF);
    float* out2  = (float*)(ws + OUT2_OFF);

    k_preproc<<<dim3(8448), dim3(256), 0, stream>>>(ew, x, ewt, bthi, btlo,
                                                    xn, xnlo, meta, nredo);
    k_dft_gemm<<<dim3(512), dim3(256), 0, stream>>>(xn, xnlo, bthi, btlo, Iout);
    k_gatefin<<<dim3(NROWS / 4), dim3(256), 0, stream>>>(Iout, gw, gb, meta, eidx,
                                                         redo, nredo);
    k_gate64<<<dim3(64), dim3(256), 0, stream>>>(x, gw, gb, meta, eidx, redo, nredo);
    k_count<<<dim3(32), dim3(256), 0, stream>>>(eidx, bhist);
    k_scan<<<dim3(1), dim3(64), 0, stream>>>(bhist, counts, offs, tdesc, base);
    k_scatter<<<dim3(32), dim3(256), 0, stream>>>(eidx, base, lists);
    k_expert_gemm<<<dim3(1920), dim3(256), 0, stream>>>(
        xn, ewt, eb, meta, lists, offs, counts, tdesc, out, out2);
    k_merge<<<dim3(NROWS * PRED / 1024), dim3(256), 0, stream>>>(out, out2);
}